// Round 7
// baseline (846.077 us; speedup 1.0000x reference)
//
#include <hip/hip_runtime.h>
#include <math.h>

#define NB 512
#define NI 8192
#define CH 8

__device__ __forceinline__ float fexp2(float x) { return __builtin_amdgcn_exp2f(x); }
__device__ __forceinline__ float flog2(float x) { return __builtin_amdgcn_logf(x); }

#define L2E 1.44269504088896340736f  // log2(e)
#define LN2 0.69314718055994530942f  // ln(2)

// ---------------- prep: lp, lq -> ws; lu = ln(noise) -> d_out (R6-verified) ----------
__global__ __launch_bounds__(256) void prep3_kernel(const float* __restrict__ logits,
                                                    const float* __restrict__ noise,
                                                    float* __restrict__ Alp,
                                                    float* __restrict__ Blq,
                                                    float* __restrict__ Clu) {
    int idx = blockIdx.x * blockDim.x + threadIdx.x;
    float4 x4 = ((const float4*)logits)[idx];
    float4 u4 = ((const float4*)noise)[idx];
    float4 lp4, lq4, lu4;
#pragma unroll
    for (int j = 0; j < 4; ++j) {
        float x = (&x4.x)[j];
        float ex = fexp2(fabsf(x) * -L2E);
        float lx = flog2(1.0f + ex);
        float mx = fmaxf(-x, 0.0f);
        float sp = fmaf(lx, LN2, mx);
        float lp = fminf(-sp, -1e-7f);
        float el = fexp2(lp * L2E);
        float lq = flog2(1.0f - el) * LN2;
        (&lp4.x)[j] = lp;
        (&lq4.x)[j] = lq;
        (&lu4.x)[j] = flog2((&u4.x)[j]) * LN2;  // u==0 -> -inf -> always fires
    }
    ((float4*)Alp)[idx] = lp4;
    ((float4*)Blq)[idx] = lq4;
    ((float4*)Clu)[idx] = lu4;
}

// ---------------- scan: 2 rows/lane, interleaved chains (numerics == R6 stepA) -------
__device__ __forceinline__ void stepY(float lp, float lq, float lu, int idx,
                                      float& S0, float& S1, int& sel,
                                      float& p0_1, float& lu_1) {
    float x1 = S0 + lp;
    float x2 = S1 + lq;
    float d  = x1 - x2;                    // never NaN: x1 always finite
    float m  = fmaxf(x1, x2);
    float e  = fexp2(fabsf(d) * -L2E);     // exp2(-inf)=0 handles S1=-inf start
    sel = (lu_1 < p0_1) ? (idx - 1) : sel; // decision of item idx-1 (in exp shadow)
    float a  = 1.0f + e;
    float l  = flog2(a);
    S1 = fmaf(l, LN2, m);                  // logaddexp(x1,x2)
    S0 = S0 + lq;
    p0_1 = x1 - S1;                        // current item's log-prob (off-chain)
    lu_1 = lu;
}

__device__ __forceinline__ void loadch(float* P, float* Q, float* U,
                                       const float* lpp, const float* lqq,
                                       const float* luu, int off) {
#pragma unroll
    for (int j = 0; j < CH / 4; ++j) {
        *(float4*)&P[4 * j] = *(const float4*)&lpp[off + 4 * j];
        *(float4*)&Q[4 * j] = *(const float4*)&lqq[off + 4 * j];
        *(float4*)&U[4 * j] = *(const float4*)&luu[off + 4 * j];
    }
}

__device__ __forceinline__ void compch2(const float* Pa, const float* Qa, const float* Ua,
                                        const float* Pb, const float* Qb, const float* Ub,
                                        int base,
                                        float& S0a, float& S1a, int& sela, float& p0a, float& lua,
                                        float& S0b, float& S1b, int& selb, float& p0b, float& lub) {
#pragma unroll
    for (int j = 0; j < CH; ++j) {
        stepY(Pa[j], Qa[j], Ua[j], base + j, S0a, S1a, sela, p0a, lua);
        stepY(Pb[j], Qb[j], Ub[j], base + j, S0b, S1b, selb, p0b, lub);
    }
}

__global__ __launch_bounds__(64, 1) void scan2_kernel(const float* __restrict__ LP,
                                                      const float* __restrict__ LQ,
                                                      const float* __restrict__ LU,
                                                      int* __restrict__ selout) {
    int lane = threadIdx.x;
    int rA = blockIdx.x * 128 + lane;
    int rB = rA + 64;
    const float *lpA = LP + (size_t)rA * NI, *lqA = LQ + (size_t)rA * NI, *luA = LU + (size_t)rA * NI;
    const float *lpB = LP + (size_t)rB * NI, *lqB = LQ + (size_t)rB * NI, *luB = LU + (size_t)rB * NI;

    float S0a = 0.0f, S1a = -INFINITY, p0a = -INFINITY, lua = 0.0f;
    float S0b = 0.0f, S1b = -INFINITY, p0b = -INFINITY, lub = 0.0f;
    int sela = 0, selb = 0;

    float pa0[CH], qa0[CH], ua0[CH], pb0[CH], qb0[CH], ub0[CH];
    float pa1[CH], qa1[CH], ua1[CH], pb1[CH], qb1[CH], ub1[CH];

    loadch(pa0, qa0, ua0, lpA, lqA, luA, 0);
    loadch(pb0, qb0, ub0, lpB, lqB, luB, 0);

    const int NCHUNK = NI / CH;  // 1024 (even)
    for (int c = 0; c < NCHUNK; c += 2) {
        const int b0 = c * CH, b1 = (c + 1) * CH, b2 = (c + 2) * CH;

        loadch(pa1, qa1, ua1, lpA, lqA, luA, b1);
        loadch(pb1, qb1, ub1, lpB, lqB, luB, b1);
        compch2(pa0, qa0, ua0, pb0, qb0, ub0, b0,
                S0a, S1a, sela, p0a, lua, S0b, S1b, selb, p0b, lub);

        if (c + 2 < NCHUNK) {
            loadch(pa0, qa0, ua0, lpA, lqA, luA, b2);
            loadch(pb0, qb0, ub0, lpB, lqB, luB, b2);
        }
        compch2(pa1, qa1, ua1, pb1, qb1, ub1, b1,
                S0a, S1a, sela, p0a, lua, S0b, S1b, selb, p0b, lub);
    }
    // flush last decisions (item NI-1)
    sela = (lua < p0a) ? (NI - 1) : sela;
    selb = (lub < p0b) ? (NI - 1) : selb;

    // write sel into each row's OWN lp[row][0] slot (read only by this block, long done)
    selout[(size_t)rA * NI] = sela;
    selout[(size_t)rB * NI] = selb;
}

// ---------------- writer: fully parallel one-hot emit ----------------
__global__ __launch_bounds__(256) void write_kernel(const int* __restrict__ selarr,
                                                    float* __restrict__ out) {
    int row = blockIdx.x;
    int s = selarr[(size_t)row * NI];
    float4* orow = (float4*)(out + (size_t)row * NI);
    int tid = threadIdx.x;
#pragma unroll
    for (int k = 0; k < NI / 4 / 256; ++k) {  // 8
        int g = k * 256 + tid;
        int i0 = 4 * g;
        float4 v;
        v.x = (i0     == s) ? 1.0f : 0.0f;
        v.y = (i0 + 1 == s) ? 1.0f : 0.0f;
        v.z = (i0 + 2 == s) ? 1.0f : 0.0f;
        v.w = (i0 + 3 == s) ? 1.0f : 0.0f;
        orow[g] = v;
    }
}

// ================= fallback (ws < 32 MB): R5/R6-verified PATH B =======================
__global__ __launch_bounds__(256) void prep_kernel(const float* __restrict__ logits,
                                                   float* __restrict__ Alp,
                                                   float* __restrict__ Blq) {
    int idx = blockIdx.x * blockDim.x + threadIdx.x;
    float4 x4 = ((const float4*)logits)[idx];
    float4 lp4, lq4;
#pragma unroll
    for (int j = 0; j < 4; ++j) {
        float x = (&x4.x)[j];
        float ex = fexp2(fabsf(x) * -L2E);
        float lx = flog2(1.0f + ex);
        float mx = fmaxf(-x, 0.0f);
        float sp = fmaf(lx, LN2, mx);
        float lp = fminf(-sp, -1e-7f);
        float el = fexp2(lp * L2E);
        float lq = flog2(1.0f - el) * LN2;
        (&lp4.x)[j] = lp;
        (&lq4.x)[j] = lq;
    }
    ((float4*)Alp)[idx] = lp4;
    ((float4*)Blq)[idx] = lq4;
}

__device__ __forceinline__ void stepB(float lp, float lq, float u, int idx,
                                      float& S0, float& S1, int& sel,
                                      float& p0_1, float& prob_2,
                                      float& u_1, float& u_2) {
    float x1 = S0 + lp;
    float x2 = S1 + lq;
    float d  = x1 - x2;
    float m  = fmaxf(x1, x2);
    float e  = fexp2(fabsf(d) * -L2E);
    sel = (u_2 < prob_2) ? (idx - 2) : sel;
    float prob_1 = fexp2(p0_1 * L2E);
    float a  = 1.0f + e;
    float l  = flog2(a);
    S1 = fmaf(l, LN2, m);
    S0 = S0 + lq;
    prob_2 = prob_1;
    u_2 = u_1;
    u_1 = u;
    p0_1 = x1 - S1;
}

__global__ __launch_bounds__(64, 1) void scanB_kernel(const float* __restrict__ A,
                                                      const float* __restrict__ B,
                                                      const float* __restrict__ noise,
                                                      float* __restrict__ out) {
    int lane = threadIdx.x;
    int row  = blockIdx.x * 64 + lane;
    const float* lpr = A + (size_t)row * NI;
    const float* lqr = B + (size_t)row * NI;
    const float* ur  = noise + (size_t)row * NI;
    float S0 = 0.0f, S1 = -INFINITY;
    int sel = 0;
    float p0_1 = -INFINITY, prob_2 = 0.0f, u_1 = 1.0f, u_2 = 1.0f;
    float lpA[16], lqA[16], uA[16], lpB[16], lqB[16], uB[16];
#pragma unroll
    for (int j = 0; j < 4; ++j) {
        *(float4*)&lpA[4 * j] = *(const float4*)&lpr[4 * j];
        *(float4*)&lqA[4 * j] = *(const float4*)&lqr[4 * j];
        *(float4*)&uA[4 * j]  = *(const float4*)&ur[4 * j];
    }
    const int NCHUNK = NI / 16;
    for (int c = 0; c < NCHUNK; c += 2) {
        const int base0 = c * 16, base1 = (c + 1) * 16, base2 = (c + 2) * 16;
#pragma unroll
        for (int j = 0; j < 4; ++j) {
            *(float4*)&lpB[4 * j] = *(const float4*)&lpr[base1 + 4 * j];
            *(float4*)&lqB[4 * j] = *(const float4*)&lqr[base1 + 4 * j];
            *(float4*)&uB[4 * j]  = *(const float4*)&ur[base1 + 4 * j];
        }
#pragma unroll
        for (int j = 0; j < 16; ++j)
            stepB(lpA[j], lqA[j], uA[j], base0 + j, S0, S1, sel, p0_1, prob_2, u_1, u_2);
        if (c + 2 < NCHUNK) {
#pragma unroll
            for (int j = 0; j < 4; ++j) {
                *(float4*)&lpA[4 * j] = *(const float4*)&lpr[base2 + 4 * j];
                *(float4*)&lqA[4 * j] = *(const float4*)&lqr[base2 + 4 * j];
                *(float4*)&uA[4 * j]  = *(const float4*)&ur[base2 + 4 * j];
            }
        }
#pragma unroll
        for (int j = 0; j < 16; ++j)
            stepB(lpB[j], lqB[j], uB[j], base1 + j, S0, S1, sel, p0_1, prob_2, u_1, u_2);
    }
    sel = (u_2 < prob_2) ? (NI - 2) : sel;
    float prob_last = fexp2(p0_1 * L2E);
    sel = (u_1 < prob_last) ? (NI - 1) : sel;

    __shared__ int sel_s[64];
    sel_s[lane] = sel;
    __syncthreads();
    float4* outb = (float4*)(out + (size_t)blockIdx.x * 64 * NI);
    for (int r = 0; r < 64; ++r) {
        int s = sel_s[r];
        float4* orow = outb + (size_t)r * (NI / 4);
#pragma unroll
        for (int k = 0; k < NI / 4 / 64; ++k) {
            int g = k * 64 + lane;
            int i0 = 4 * g;
            float4 v;
            v.x = (i0     == s) ? 1.0f : 0.0f;
            v.y = (i0 + 1 == s) ? 1.0f : 0.0f;
            v.z = (i0 + 2 == s) ? 1.0f : 0.0f;
            v.w = (i0 + 3 == s) ? 1.0f : 0.0f;
            orow[g] = v;
        }
    }
}

extern "C" void kernel_launch(void* const* d_in, const int* in_sizes, int n_in,
                              void* d_out, int out_size, void* d_ws, size_t ws_size,
                              hipStream_t stream) {
    (void)in_sizes; (void)n_in; (void)out_size;
    const float* logits = (const float*)d_in[0];
    const float* noise  = (const float*)d_in[1];
    float* out = (float*)d_out;
    float* ws  = (float*)d_ws;

    const size_t STREAM_ELEMS = (size_t)NB * NI;
    int total4 = NB * NI / 4;

    if (ws_size >= 2 * STREAM_ELEMS * sizeof(float)) {
        float* lp = ws;
        float* lq = ws + STREAM_ELEMS;
        prep3_kernel<<<total4 / 256, 256, 0, stream>>>(logits, noise, lp, lq, out);
        scan2_kernel<<<NB / 128, 64, 0, stream>>>(lp, lq, out, (int*)ws);
        write_kernel<<<NB, 256, 0, stream>>>((const int*)ws, out);
    } else {
        prep_kernel<<<total4 / 256, 256, 0, stream>>>(logits, ws, out);
        scanB_kernel<<<NB / 64, 64, 0, stream>>>(ws, out, noise, out);
    }
}